// Round 9
// baseline (130.183 us; speedup 1.0000x reference)
//
#include <hip/hip_runtime.h>
#include <hip/hip_bf16.h>

#define E_ 8
#define B_ 8
#define S_ 2048
#define D_ 512
#define R_ 128
#define M_TOT (B_ * S_)   // 16384

typedef __attribute__((ext_vector_type(8))) short bf16x8;
typedef __attribute__((ext_vector_type(4))) float f32x4;

__device__ __forceinline__ void gload_lds16(void* lds, const void* g) {
  __builtin_amdgcn_global_load_lds(
      (const __attribute__((address_space(1))) void*)g,
      (__attribute__((address_space(3))) void*)lds, 16, 0, 0);
}

// ---------------------------------------------------------------------------
// Fused prep kernel (unchanged from R5):
//   [0,16) rotation recurrence | [16,2064) W tail | [2064,6160) x -> bf16
// ---------------------------------------------------------------------------
#define ROT_B 16
#define WT_B 2048
#define CX_B 4096
__global__ __launch_bounds__(256) void prep_fused(
    const float* __restrict__ x, const float* __restrict__ theta,
    const float* __restrict__ pw, __hip_bfloat16* __restrict__ xb,
    __hip_bfloat16* __restrict__ Wb) {
  int blk = blockIdx.x;
  int t = threadIdx.x;
  if (blk < ROT_B) {
    __shared__ float cs[R_], ss[R_];
    __shared__ float Pch[256][17];
    __shared__ __hip_bfloat16 Wch[256][18];
    int e = blk >> 1;
    int r0 = (blk & 1) * 256;
    if (t < R_) {
      float a = tanhf(theta[e * R_ + t]) * 0.1f;
      cs[t] = cosf(a);
      ss[t] = sinf(a);
    }
    const float* Pe = pw + (size_t)e * D_ * D_;
    __hip_bfloat16* We = Wb + (size_t)e * D_ * D_;
    float u = Pe[(size_t)(r0 + t) * D_];
    __syncthreads();
    for (int c = 0; c < 8; ++c) {
      for (int i = t; i < 256 * 16; i += 256) {
        int row = i >> 4, col = i & 15;
        Pch[row][col] = Pe[(size_t)(r0 + row) * D_ + 1 + 16 * c + col];
      }
      __syncthreads();
#pragma unroll
      for (int kk = 0; kk < 16; ++kk) {
        int k = 16 * c + kk;
        float pj = Pch[t][kk];
        Wch[t][kk] = __float2bfloat16(cs[k] * pj - ss[k] * u);
        u = cs[k] * u + ss[k] * pj;
      }
      __syncthreads();
      for (int i = t; i < 256 * 16; i += 256) {
        int row = i >> 4, col = i & 15;
        We[(size_t)(r0 + row) * D_ + 1 + 16 * c + col] = Wch[row][col];
      }
      __syncthreads();
    }
    We[(size_t)(r0 + t) * D_] = __float2bfloat16(u);
  } else if (blk < ROT_B + WT_B) {
    int g = (blk - ROT_B) * 256 + t;
    int gidx = g & 127;
    if (gidx < 32) return;
    float4 v = ((const float4*)pw)[g];
    union { short4 s; __hip_bfloat16 h[4]; } u;
    u.h[0] = __float2bfloat16(v.x);
    u.h[1] = __float2bfloat16(v.y);
    u.h[2] = __float2bfloat16(v.z);
    u.h[3] = __float2bfloat16(v.w);
    if (gidx > 32) {
      ((short4*)Wb)[g] = u.s;
    } else {
      Wb[(size_t)g * 4 + 1] = u.h[1];
      Wb[(size_t)g * 4 + 2] = u.h[2];
      Wb[(size_t)g * 4 + 3] = u.h[3];
    }
  } else {
    int i = (blk - ROT_B - WT_B) * 256 + t;
#pragma unroll
    for (int rep = 0; rep < 2; ++rep) {
      int idx = i + rep * (CX_B * 256);
      float4 v = ((const float4*)x)[idx];
      union { short4 s; __hip_bfloat16 h[4]; } u;
      u.h[0] = __float2bfloat16(v.x);
      u.h[1] = __float2bfloat16(v.y);
      u.h[2] = __float2bfloat16(v.z);
      u.h[3] = __float2bfloat16(v.w);
      ((short4*)xb)[idx] = u.s;
    }
  }
}

// ---------------------------------------------------------------------------
// GEMM: out[e] = Xb @ Wb[e]^T (NT). MEMORY-BOUND regime (AI=224 FLOP/B <
// machine balance 397): the lever is continuous HBM streaming via >=2
// INDEPENDENT blocks/CU (one block's prologue/epilogue overlaps the other's
// K-loop). block 256x128, 4 waves (wave-tile 128x64), BK=32, 2-slot double
// buffer = 48 KB LDS, ~190 VGPR -> 2 blocks/CU. 2048 blocks = 8 rounds/CU.
// BK=32 row-major [row][32] is naturally bank-uniform for ds_read_b128
// (64B row stride) -> no swizzle, staging fully linear+coalesced.
// Counted vmcnt(6) (never drains mid-loop); lgkmcnt(0)+sched_barrier before
// restage (rule #18); raw s_barriers only. setprio around MFMA (T5).
// XCD swizzle (T1): per-XCD chunk e-major -> W[e] 512KB + A 2MB L2-resident.
// ---------------------------------------------------------------------------
__global__ __launch_bounds__(256, 2) void gemm_xw(
    const __hip_bfloat16* __restrict__ Xb,   // [M_TOT][512]
    const __hip_bfloat16* __restrict__ Wb,   // [E][512][512] rows=o, cols=d
    float* __restrict__ out)                 // [E][M_TOT][512]
{
  constexpr int BM = 256, BN = 128, BK = 32;
  constexpr int KD = D_, ND = D_;
  constexpr int NT = KD / BK;  // 16
  __shared__ __align__(16) __hip_bfloat16 As[2][BM * BK];  // 32 KB
  __shared__ __align__(16) __hip_bfloat16 Bs[2][BN * BK];  // 16 KB

  int bx = blockIdx.x;            // 2048 blocks
  int xcd = bx & 7, c = bx >> 3;  // chunk c in [0,256) per XCD
  int e = c >> 5;                 // 0..7  (e-major within XCD)
  int msub = (c >> 2) & 7;        // 0..7
  int nt = c & 3;                 // 0..3
  int mt = xcd * 8 + msub;        // 0..63

  int tid = threadIdx.x;
  int wave = tid >> 6, lane = tid & 63;
  int lr = lane & 15, lk = lane >> 4;
  int wm = wave >> 1, wn = wave & 1;   // 2x2 waves; wave-tile 128x64

  const __hip_bfloat16* Ag = Xb + (size_t)(mt * BM) * KD;
  const __hip_bfloat16* Bg = Wb + ((size_t)e * ND + (size_t)nt * BN) * KD;

  // staging: lane -> (row = lane>>2 of 16, chunk = lane&3); linear LDS dest.
  int srow = lane >> 2;
  int scol = (lane & 3) * 8;

  // fragment reads: addr = row*64B + lk*16B (bank-uniform at 64B stride)
  int aoff = (wm * 128 + lr) * BK + lk * 8;
  int boff = (wn * 64 + lr) * BK + lk * 8;

  f32x4 acc[8][4];
#pragma unroll
  for (int i = 0; i < 8; ++i)
#pragma unroll
    for (int j = 0; j < 4; ++j) acc[i][j] = (f32x4){0.f, 0.f, 0.f, 0.f};

  // per wave per tile: A 4 gloads (64 rows), B 2 gloads (32 rows) = 6 loads
#define STAGE(buf, t)                                                        \
  {                                                                          \
    _Pragma("unroll") for (int g = 0; g < 4; ++g) {                          \
      int rb = wave * 64 + g * 16;                                           \
      gload_lds16(&As[buf][rb * BK],                                         \
                  Ag + (size_t)(rb + srow) * KD + (t) * BK + scol);          \
    }                                                                        \
    _Pragma("unroll") for (int g = 0; g < 2; ++g) {                          \
      int rb = wave * 32 + g * 16;                                           \
      gload_lds16(&Bs[buf][rb * BK],                                         \
                  Bg + (size_t)(rb + srow) * KD + (t) * BK + scol);          \
    }                                                                        \
  }

  STAGE(0, 0);
  STAGE(1, 1);

#pragma unroll
  for (int t = 0; t < NT; ++t) {
    int buf = t & 1;
    // tile t resident once <=6 newer loads (tile t+1) remain in flight
    if (t < NT - 1) {
      asm volatile("s_waitcnt vmcnt(6)" ::: "memory");
    } else {
      asm volatile("s_waitcnt vmcnt(0)" ::: "memory");
    }
    __builtin_amdgcn_s_barrier();   // tile t visible to all 4 waves

    bf16x8 af[8], bfr[4];
#pragma unroll
    for (int ni = 0; ni < 4; ++ni)
      bfr[ni] = *(const bf16x8*)&Bs[buf][boff + ni * 16 * BK];
#pragma unroll
    for (int mi = 0; mi < 8; ++mi)
      af[mi] = *(const bf16x8*)&As[buf][aoff + mi * 16 * BK];
    __builtin_amdgcn_s_setprio(1);
#pragma unroll
    for (int mi = 0; mi < 8; ++mi)
#pragma unroll
      for (int ni = 0; ni < 4; ++ni)
        acc[mi][ni] = __builtin_amdgcn_mfma_f32_16x16x32_bf16(
            af[mi], bfr[ni], acc[mi][ni], 0, 0, 0);
    __builtin_amdgcn_s_setprio(0);

    // all ds_reads of this tile drained before DMA may overwrite the slot
    asm volatile("s_waitcnt lgkmcnt(0)" ::: "memory");
    __builtin_amdgcn_sched_barrier(0);
    __builtin_amdgcn_s_barrier();
    if (t + 2 < NT) STAGE(buf, t + 2);
  }
#undef STAGE

  // epilogue: C/D layout col = lane&15, row = (lane>>4)*4 + reg  [m89]
  size_t obase = (size_t)e * M_TOT * ND;
  int row0 = mt * BM + wm * 128;
  int col0 = nt * BN + wn * 64;
#pragma unroll
  for (int mi = 0; mi < 8; ++mi)
#pragma unroll
    for (int ni = 0; ni < 4; ++ni) {
      int r0 = row0 + mi * 16 + lk * 4;
      int cc = col0 + ni * 16 + lr;
      float* op = out + obase + (size_t)r0 * ND + cc;
#pragma unroll
      for (int q = 0; q < 4; ++q) op[(size_t)q * ND] = acc[mi][ni][q];
    }
}

extern "C" void kernel_launch(void* const* d_in, const int* in_sizes, int n_in,
                              void* d_out, int out_size, void* d_ws, size_t ws_size,
                              hipStream_t stream) {
  const float* x = (const float*)d_in[0];        // [B][S][D] f32
  const float* theta = (const float*)d_in[1];    // [E][R] f32
  const float* proj_w = (const float*)d_in[2];   // [E][D][D] f32
  float* out = (float*)d_out;                    // [E][B][S][D] f32

  __hip_bfloat16* xb = (__hip_bfloat16*)d_ws;                          // 16 MB
  __hip_bfloat16* Wb = (__hip_bfloat16*)((char*)d_ws +
                        (size_t)M_TOT * D_ * sizeof(__hip_bfloat16));  // 4 MB

  hipLaunchKernelGGL(prep_fused, dim3(ROT_B + WT_B + CX_B), dim3(256), 0,
                     stream, x, theta, proj_w, xb, Wb);
  // grid: (M_TOT/256)=64 mt  x  8 e  x  (512/128)=4 nt  = 2048 blocks
  hipLaunchKernelGGL(gemm_xw, dim3(2048), dim3(256), 0, stream, xb, Wb, out);
}

// Round 10
// 116.011 us; speedup vs baseline: 1.1222x; 1.1222x over previous
//
#include <hip/hip_runtime.h>
#include <hip/hip_bf16.h>

#define E_ 8
#define B_ 8
#define S_ 2048
#define D_ 512
#define R_ 128
#define M_TOT (B_ * S_)   // 16384

typedef __attribute__((ext_vector_type(8))) short bf16x8;
typedef __attribute__((ext_vector_type(4))) float f32x4;

__device__ __forceinline__ void gload_lds16(void* lds, const void* g) {
  __builtin_amdgcn_global_load_lds(
      (const __attribute__((address_space(1))) void*)g,
      (__attribute__((address_space(3))) void*)lds, 16, 0, 0);
}

// ---------------------------------------------------------------------------
// Fused prep kernel (unchanged from R5):
//   [0,16) rotation recurrence | [16,2064) W tail | [2064,6160) x -> bf16
// ---------------------------------------------------------------------------
#define ROT_B 16
#define WT_B 2048
#define CX_B 4096
__global__ __launch_bounds__(256) void prep_fused(
    const float* __restrict__ x, const float* __restrict__ theta,
    const float* __restrict__ pw, __hip_bfloat16* __restrict__ xb,
    __hip_bfloat16* __restrict__ Wb) {
  int blk = blockIdx.x;
  int t = threadIdx.x;
  if (blk < ROT_B) {
    __shared__ float cs[R_], ss[R_];
    __shared__ float Pch[256][17];
    __shared__ __hip_bfloat16 Wch[256][18];
    int e = blk >> 1;
    int r0 = (blk & 1) * 256;
    if (t < R_) {
      float a = tanhf(theta[e * R_ + t]) * 0.1f;
      cs[t] = cosf(a);
      ss[t] = sinf(a);
    }
    const float* Pe = pw + (size_t)e * D_ * D_;
    __hip_bfloat16* We = Wb + (size_t)e * D_ * D_;
    float u = Pe[(size_t)(r0 + t) * D_];
    __syncthreads();
    for (int c = 0; c < 8; ++c) {
      for (int i = t; i < 256 * 16; i += 256) {
        int row = i >> 4, col = i & 15;
        Pch[row][col] = Pe[(size_t)(r0 + row) * D_ + 1 + 16 * c + col];
      }
      __syncthreads();
#pragma unroll
      for (int kk = 0; kk < 16; ++kk) {
        int k = 16 * c + kk;
        float pj = Pch[t][kk];
        Wch[t][kk] = __float2bfloat16(cs[k] * pj - ss[k] * u);
        u = cs[k] * u + ss[k] * pj;
      }
      __syncthreads();
      for (int i = t; i < 256 * 16; i += 256) {
        int row = i >> 4, col = i & 15;
        We[(size_t)(r0 + row) * D_ + 1 + 16 * c + col] = Wch[row][col];
      }
      __syncthreads();
    }
    We[(size_t)(r0 + t) * D_] = __float2bfloat16(u);
  } else if (blk < ROT_B + WT_B) {
    int g = (blk - ROT_B) * 256 + t;
    int gidx = g & 127;
    if (gidx < 32) return;
    float4 v = ((const float4*)pw)[g];
    union { short4 s; __hip_bfloat16 h[4]; } u;
    u.h[0] = __float2bfloat16(v.x);
    u.h[1] = __float2bfloat16(v.y);
    u.h[2] = __float2bfloat16(v.z);
    u.h[3] = __float2bfloat16(v.w);
    if (gidx > 32) {
      ((short4*)Wb)[g] = u.s;
    } else {
      Wb[(size_t)g * 4 + 1] = u.h[1];
      Wb[(size_t)g * 4 + 2] = u.h[2];
      Wb[(size_t)g * 4 + 3] = u.h[3];
    }
  } else {
    int i = (blk - ROT_B - WT_B) * 256 + t;
#pragma unroll
    for (int rep = 0; rep < 2; ++rep) {
      int idx = i + rep * (CX_B * 256);
      float4 v = ((const float4*)x)[idx];
      union { short4 s; __hip_bfloat16 h[4]; } u;
      u.h[0] = __float2bfloat16(v.x);
      u.h[1] = __float2bfloat16(v.y);
      u.h[2] = __float2bfloat16(v.z);
      u.h[3] = __float2bfloat16(v.w);
      ((short4*)xb)[idx] = u.s;
    }
  }
}

// ---------------------------------------------------------------------------
// GEMM: out[e] = Xb @ Wb[e]^T (NT). K-loop identical to R9 (256x128 block,
// 4 waves, BK=32 double buffer, counted vmcnt(6), 2 blocks/CU, T1/T5).
// NEW: write-coalesced epilogue — C staged through LDS (padded stride 132)
// in 4 rounds of 32 rows, stored as global_store_dwordx4 with 64 consecutive
// lanes (two 512B aligned segments / instruction, full lines, 32 stores per
// thread instead of 128 scattered dwords) — the fill-kernel access pattern.
// ---------------------------------------------------------------------------
__global__ __launch_bounds__(256, 2) void gemm_xw(
    const __hip_bfloat16* __restrict__ Xb,   // [M_TOT][512]
    const __hip_bfloat16* __restrict__ Wb,   // [E][512][512] rows=o, cols=d
    float* __restrict__ out)                 // [E][M_TOT][512]
{
  constexpr int BM = 256, BN = 128, BK = 32;
  constexpr int KD = D_, ND = D_;
  constexpr int NT = KD / BK;  // 16
  // 48 KB shared pool: K-loop uses As(32K)+Bs(16K); epilogue reuses 33.8K.
  __shared__ __align__(16) char smem[49152];
  __hip_bfloat16 (*As)[BM * BK] =
      (__hip_bfloat16 (*)[BM * BK]) & smem[0];         // 2 x 16 KB
  __hip_bfloat16 (*Bs)[BN * BK] =
      (__hip_bfloat16 (*)[BN * BK]) & smem[32768];     // 2 x 8 KB
  float* Lep = (float*)&smem[0];                       // epilogue: 2x32x132 f32

  int bx = blockIdx.x;            // 2048 blocks
  int xcd = bx & 7, c = bx >> 3;  // chunk c in [0,256) per XCD
  int e = c >> 5;                 // 0..7  (e-major within XCD)
  int msub = (c >> 2) & 7;        // 0..7
  int nt = c & 3;                 // 0..3
  int mt = xcd * 8 + msub;        // 0..63

  int tid = threadIdx.x;
  int wave = tid >> 6, lane = tid & 63;
  int lr = lane & 15, lk = lane >> 4;
  int wm = wave >> 1, wn = wave & 1;   // 2x2 waves; wave-tile 128x64

  const __hip_bfloat16* Ag = Xb + (size_t)(mt * BM) * KD;
  const __hip_bfloat16* Bg = Wb + ((size_t)e * ND + (size_t)nt * BN) * KD;

  // staging: lane -> (row = lane>>2 of 16, chunk = lane&3); linear LDS dest.
  int srow = lane >> 2;
  int scol = (lane & 3) * 8;

  // fragment reads: addr = row*64B + lk*16B (bank-uniform at 64B stride)
  int aoff = (wm * 128 + lr) * BK + lk * 8;
  int boff = (wn * 64 + lr) * BK + lk * 8;

  f32x4 acc[8][4];
#pragma unroll
  for (int i = 0; i < 8; ++i)
#pragma unroll
    for (int j = 0; j < 4; ++j) acc[i][j] = (f32x4){0.f, 0.f, 0.f, 0.f};

  // per wave per tile: A 4 gloads (64 rows), B 2 gloads (32 rows) = 6 loads
#define STAGE(buf, t)                                                        \
  {                                                                          \
    _Pragma("unroll") for (int g = 0; g < 4; ++g) {                          \
      int rb = wave * 64 + g * 16;                                           \
      gload_lds16(&As[buf][rb * BK],                                         \
                  Ag + (size_t)(rb + srow) * KD + (t) * BK + scol);          \
    }                                                                        \
    _Pragma("unroll") for (int g = 0; g < 2; ++g) {                          \
      int rb = wave * 32 + g * 16;                                           \
      gload_lds16(&Bs[buf][rb * BK],                                         \
                  Bg + (size_t)(rb + srow) * KD + (t) * BK + scol);          \
    }                                                                        \
  }

  STAGE(0, 0);
  STAGE(1, 1);

#pragma unroll
  for (int t = 0; t < NT; ++t) {
    int buf = t & 1;
    // tile t resident once <=6 newer loads (tile t+1) remain in flight
    if (t < NT - 1) {
      asm volatile("s_waitcnt vmcnt(6)" ::: "memory");
    } else {
      asm volatile("s_waitcnt vmcnt(0)" ::: "memory");
    }
    __builtin_amdgcn_s_barrier();   // tile t visible to all 4 waves

    bf16x8 af[8], bfr[4];
#pragma unroll
    for (int ni = 0; ni < 4; ++ni)
      bfr[ni] = *(const bf16x8*)&Bs[buf][boff + ni * 16 * BK];
#pragma unroll
    for (int mi = 0; mi < 8; ++mi)
      af[mi] = *(const bf16x8*)&As[buf][aoff + mi * 16 * BK];
    __builtin_amdgcn_s_setprio(1);
#pragma unroll
    for (int mi = 0; mi < 8; ++mi)
#pragma unroll
      for (int ni = 0; ni < 4; ++ni)
        acc[mi][ni] = __builtin_amdgcn_mfma_f32_16x16x32_bf16(
            af[mi], bfr[ni], acc[mi][ni], 0, 0, 0);
    __builtin_amdgcn_s_setprio(0);

    // all ds_reads of this tile drained before DMA may overwrite the slot
    asm volatile("s_waitcnt lgkmcnt(0)" ::: "memory");
    __builtin_amdgcn_sched_barrier(0);
    __builtin_amdgcn_s_barrier();
    if (t + 2 < NT) STAGE(buf, t + 2);
  }
#undef STAGE

  // ---- write-coalesced epilogue ----
  // C/D frag layout: col = lane&15 (lr), row = lk*4 + q   [m89]
  // Round r covers block-rows [wm*128 + r*32, +32). LDS half per wm pair:
  // Lh[32][132] (pad 4 floats: ds_write 2-way max, readback conflict-free).
  size_t obase = (size_t)e * M_TOT * ND;
  int row0 = mt * BM;
  int col0 = nt * BN;
  float* Lh = Lep + (size_t)wm * (32 * 132);
#pragma unroll
  for (int r = 0; r < 4; ++r) {
#pragma unroll
    for (int m2 = 0; m2 < 2; ++m2) {
      int mi = 2 * r + m2;
#pragma unroll
      for (int ni = 0; ni < 4; ++ni)
#pragma unroll
        for (int q = 0; q < 4; ++q)
          Lh[(m2 * 16 + lk * 4 + q) * 132 + wn * 64 + ni * 16 + lr] =
              acc[mi][ni][q];
    }
    __builtin_amdgcn_s_barrier();
    // readback: wave wn covers LDS rows [wn*16, +16); lanes 0..31 = one row
    // (512B contiguous), lanes 32..63 = next row.
#pragma unroll
    for (int j = 0; j < 8; ++j) {
      int lrow = wn * 16 + j * 2 + (lane >> 5);
      int lc4 = lane & 31;
      float4 v = *(const float4*)&Lh[lrow * 132 + lc4 * 4];
      int grow = row0 + wm * 128 + r * 32 + lrow;
      *(float4*)&out[obase + (size_t)grow * ND + col0 + lc4 * 4] = v;
    }
    __builtin_amdgcn_s_barrier();
  }
}

extern "C" void kernel_launch(void* const* d_in, const int* in_sizes, int n_in,
                              void* d_out, int out_size, void* d_ws, size_t ws_size,
                              hipStream_t stream) {
  const float* x = (const float*)d_in[0];        // [B][S][D] f32
  const float* theta = (const float*)d_in[1];    // [E][R] f32
  const float* proj_w = (const float*)d_in[2];   // [E][D][D] f32
  float* out = (float*)d_out;                    // [E][B][S][D] f32

  __hip_bfloat16* xb = (__hip_bfloat16*)d_ws;                          // 16 MB
  __hip_bfloat16* Wb = (__hip_bfloat16*)((char*)d_ws +
                        (size_t)M_TOT * D_ * sizeof(__hip_bfloat16));  // 4 MB

  hipLaunchKernelGGL(prep_fused, dim3(ROT_B + WT_B + CX_B), dim3(256), 0,
                     stream, x, theta, proj_w, xb, Wb);
  // grid: (M_TOT/256)=64 mt  x  8 e  x  (512/128)=4 nt  = 2048 blocks
  hipLaunchKernelGGL(gemm_xw, dim3(2048), dim3(256), 0, stream, xb, Wb, out);
}

// Round 12
// 104.909 us; speedup vs baseline: 1.2409x; 1.1058x over previous
//
#include <hip/hip_runtime.h>
#include <hip/hip_bf16.h>

#define E_ 8
#define B_ 8
#define S_ 2048
#define D_ 512
#define R_ 128
#define M_TOT (B_ * S_)   // 16384

typedef __attribute__((ext_vector_type(8))) short bf16x8;
typedef __attribute__((ext_vector_type(4))) float f32x4;
typedef __attribute__((ext_vector_type(4))) short s16x4;

__device__ __forceinline__ void gload_lds16(void* lds, const void* g) {
  __builtin_amdgcn_global_load_lds(
      (const __attribute__((address_space(1))) void*)g,
      (__attribute__((address_space(3))) void*)lds, 16, 0, 0);
}

// ---------------------------------------------------------------------------
// Fused prep kernel (R5 structure; x loads nontemporal — read-once stream):
//   [0,16) rotation recurrence | [16,2064) W tail | [2064,6160) x -> bf16
// ---------------------------------------------------------------------------
#define ROT_B 16
#define WT_B 2048
#define CX_B 4096
__global__ __launch_bounds__(256) void prep_fused(
    const float* __restrict__ x, const float* __restrict__ theta,
    const float* __restrict__ pw, __hip_bfloat16* __restrict__ xb,
    __hip_bfloat16* __restrict__ Wb) {
  int blk = blockIdx.x;
  int t = threadIdx.x;
  if (blk < ROT_B) {
    __shared__ float cs[R_], ss[R_];
    __shared__ float Pch[256][17];
    __shared__ __hip_bfloat16 Wch[256][18];
    int e = blk >> 1;
    int r0 = (blk & 1) * 256;
    if (t < R_) {
      float a = tanhf(theta[e * R_ + t]) * 0.1f;
      cs[t] = cosf(a);
      ss[t] = sinf(a);
    }
    const float* Pe = pw + (size_t)e * D_ * D_;
    __hip_bfloat16* We = Wb + (size_t)e * D_ * D_;
    float u = Pe[(size_t)(r0 + t) * D_];
    __syncthreads();
    for (int c = 0; c < 8; ++c) {
      for (int i = t; i < 256 * 16; i += 256) {
        int row = i >> 4, col = i & 15;
        Pch[row][col] = Pe[(size_t)(r0 + row) * D_ + 1 + 16 * c + col];
      }
      __syncthreads();
#pragma unroll
      for (int kk = 0; kk < 16; ++kk) {
        int k = 16 * c + kk;
        float pj = Pch[t][kk];
        Wch[t][kk] = __float2bfloat16(cs[k] * pj - ss[k] * u);
        u = cs[k] * u + ss[k] * pj;
      }
      __syncthreads();
      for (int i = t; i < 256 * 16; i += 256) {
        int row = i >> 4, col = i & 15;
        We[(size_t)(r0 + row) * D_ + 1 + 16 * c + col] = Wch[row][col];
      }
      __syncthreads();
    }
    We[(size_t)(r0 + t) * D_] = __float2bfloat16(u);
  } else if (blk < ROT_B + WT_B) {
    int g = (blk - ROT_B) * 256 + t;
    int gidx = g & 127;
    if (gidx < 32) return;
    float4 v = ((const float4*)pw)[g];
    union { short4 s; __hip_bfloat16 h[4]; } u;
    u.h[0] = __float2bfloat16(v.x);
    u.h[1] = __float2bfloat16(v.y);
    u.h[2] = __float2bfloat16(v.z);
    u.h[3] = __float2bfloat16(v.w);
    if (gidx > 32) {
      ((short4*)Wb)[g] = u.s;
    } else {
      Wb[(size_t)g * 4 + 1] = u.h[1];
      Wb[(size_t)g * 4 + 2] = u.h[2];
      Wb[(size_t)g * 4 + 3] = u.h[3];
    }
  } else {
    int i = (blk - ROT_B - WT_B) * 256 + t;
#pragma unroll
    for (int rep = 0; rep < 2; ++rep) {
      int idx = i + rep * (CX_B * 256);
      f32x4 v = __builtin_nontemporal_load(&((const f32x4*)x)[idx]);
      union { s16x4 s; __hip_bfloat16 h[4]; } u;
      u.h[0] = __float2bfloat16(v.x);
      u.h[1] = __float2bfloat16(v.y);
      u.h[2] = __float2bfloat16(v.z);
      u.h[3] = __float2bfloat16(v.w);
      ((s16x4*)xb)[idx] = u.s;
    }
  }
}

// ---------------------------------------------------------------------------
// GEMM: out[e] = Xb @ Wb[e]^T (NT). K-loop identical to R9/R10 (256x128
// block, 4 waves, BK=32 double buffer, counted vmcnt(6), 2 blocks/CU, T1/T5).
// R10: write-coalesced LDS-staged epilogue (float4 stores, full lines).
// R12(=R11 fixed): epilogue stores NONTEMPORAL — C is written once and never
// re-read; keeping it out of L2 preserves the A-panel/W residency the XCD
// swizzle relies on (32 MB of C per XCD was thrashing the 4 MB L2).
// ---------------------------------------------------------------------------
__global__ __launch_bounds__(256, 2) void gemm_xw(
    const __hip_bfloat16* __restrict__ Xb,   // [M_TOT][512]
    const __hip_bfloat16* __restrict__ Wb,   // [E][512][512] rows=o, cols=d
    float* __restrict__ out)                 // [E][M_TOT][512]
{
  constexpr int BM = 256, BN = 128, BK = 32;
  constexpr int KD = D_, ND = D_;
  constexpr int NT = KD / BK;  // 16
  // 48 KB shared pool: K-loop uses As(32K)+Bs(16K); epilogue reuses 33.8K.
  __shared__ __align__(16) char smem[49152];
  __hip_bfloat16 (*As)[BM * BK] =
      (__hip_bfloat16 (*)[BM * BK]) & smem[0];         // 2 x 16 KB
  __hip_bfloat16 (*Bs)[BN * BK] =
      (__hip_bfloat16 (*)[BN * BK]) & smem[32768];     // 2 x 8 KB
  float* Lep = (float*)&smem[0];                       // epilogue: 2x32x132 f32

  int bx = blockIdx.x;            // 2048 blocks
  int xcd = bx & 7, c = bx >> 3;  // chunk c in [0,256) per XCD
  int e = c >> 5;                 // 0..7  (e-major within XCD)
  int msub = (c >> 2) & 7;        // 0..7
  int nt = c & 3;                 // 0..3
  int mt = xcd * 8 + msub;        // 0..63

  int tid = threadIdx.x;
  int wave = tid >> 6, lane = tid & 63;
  int lr = lane & 15, lk = lane >> 4;
  int wm = wave >> 1, wn = wave & 1;   // 2x2 waves; wave-tile 128x64

  const __hip_bfloat16* Ag = Xb + (size_t)(mt * BM) * KD;
  const __hip_bfloat16* Bg = Wb + ((size_t)e * ND + (size_t)nt * BN) * KD;

  // staging: lane -> (row = lane>>2 of 16, chunk = lane&3); linear LDS dest.
  int srow = lane >> 2;
  int scol = (lane & 3) * 8;

  // fragment reads: addr = row*64B + lk*16B (bank-uniform at 64B stride)
  int aoff = (wm * 128 + lr) * BK + lk * 8;
  int boff = (wn * 64 + lr) * BK + lk * 8;

  f32x4 acc[8][4];
#pragma unroll
  for (int i = 0; i < 8; ++i)
#pragma unroll
    for (int j = 0; j < 4; ++j) acc[i][j] = (f32x4){0.f, 0.f, 0.f, 0.f};

  // per wave per tile: A 4 gloads (64 rows), B 2 gloads (32 rows) = 6 loads
#define STAGE(buf, t)                                                        \
  {                                                                          \
    _Pragma("unroll") for (int g = 0; g < 4; ++g) {                          \
      int rb = wave * 64 + g * 16;                                           \
      gload_lds16(&As[buf][rb * BK],                                         \
                  Ag + (size_t)(rb + srow) * KD + (t) * BK + scol);          \
    }                                                                        \
    _Pragma("unroll") for (int g = 0; g < 2; ++g) {                          \
      int rb = wave * 32 + g * 16;                                           \
      gload_lds16(&Bs[buf][rb * BK],                                         \
                  Bg + (size_t)(rb + srow) * KD + (t) * BK + scol);          \
    }                                                                        \
  }

  STAGE(0, 0);
  STAGE(1, 1);

#pragma unroll
  for (int t = 0; t < NT; ++t) {
    int buf = t & 1;
    // tile t resident once <=6 newer loads (tile t+1) remain in flight
    if (t < NT - 1) {
      asm volatile("s_waitcnt vmcnt(6)" ::: "memory");
    } else {
      asm volatile("s_waitcnt vmcnt(0)" ::: "memory");
    }
    __builtin_amdgcn_s_barrier();   // tile t visible to all 4 waves

    bf16x8 af[8], bfr[4];
#pragma unroll
    for (int ni = 0; ni < 4; ++ni)
      bfr[ni] = *(const bf16x8*)&Bs[buf][boff + ni * 16 * BK];
#pragma unroll
    for (int mi = 0; mi < 8; ++mi)
      af[mi] = *(const bf16x8*)&As[buf][aoff + mi * 16 * BK];
    __builtin_amdgcn_s_setprio(1);
#pragma unroll
    for (int mi = 0; mi < 8; ++mi)
#pragma unroll
      for (int ni = 0; ni < 4; ++ni)
        acc[mi][ni] = __builtin_amdgcn_mfma_f32_16x16x32_bf16(
            af[mi], bfr[ni], acc[mi][ni], 0, 0, 0);
    __builtin_amdgcn_s_setprio(0);

    // all ds_reads of this tile drained before DMA may overwrite the slot
    asm volatile("s_waitcnt lgkmcnt(0)" ::: "memory");
    __builtin_amdgcn_sched_barrier(0);
    __builtin_amdgcn_s_barrier();
    if (t + 2 < NT) STAGE(buf, t + 2);
  }
#undef STAGE

  // ---- write-coalesced epilogue (nontemporal stores) ----
  // C/D frag layout: col = lane&15 (lr), row = lk*4 + q   [m89]
  size_t obase = (size_t)e * M_TOT * ND;
  int row0 = mt * BM;
  int col0 = nt * BN;
  float* Lh = Lep + (size_t)wm * (32 * 132);
#pragma unroll
  for (int r = 0; r < 4; ++r) {
#pragma unroll
    for (int m2 = 0; m2 < 2; ++m2) {
      int mi = 2 * r + m2;
#pragma unroll
      for (int ni = 0; ni < 4; ++ni)
#pragma unroll
        for (int q = 0; q < 4; ++q)
          Lh[(m2 * 16 + lk * 4 + q) * 132 + wn * 64 + ni * 16 + lr] =
              acc[mi][ni][q];
    }
    __builtin_amdgcn_s_barrier();
    // readback: wave wn covers LDS rows [wn*16, +16); lanes 0..31 = one row
    // (512B contiguous), lanes 32..63 = next row.
#pragma unroll
    for (int j = 0; j < 8; ++j) {
      int lrow = wn * 16 + j * 2 + (lane >> 5);
      int lc4 = lane & 31;
      f32x4 v = *(const f32x4*)&Lh[lrow * 132 + lc4 * 4];
      int grow = row0 + wm * 128 + r * 32 + lrow;
      __builtin_nontemporal_store(
          v, (f32x4*)&out[obase + (size_t)grow * ND + col0 + lc4 * 4]);
    }
    __builtin_amdgcn_s_barrier();
  }
}

extern "C" void kernel_launch(void* const* d_in, const int* in_sizes, int n_in,
                              void* d_out, int out_size, void* d_ws, size_t ws_size,
                              hipStream_t stream) {
  const float* x = (const float*)d_in[0];        // [B][S][D] f32
  const float* theta = (const float*)d_in[1];    // [E][R] f32
  const float* proj_w = (const float*)d_in[2];   // [E][D][D] f32
  float* out = (float*)d_out;                    // [E][B][S][D] f32

  __hip_bfloat16* xb = (__hip_bfloat16*)d_ws;                          // 16 MB
  __hip_bfloat16* Wb = (__hip_bfloat16*)((char*)d_ws +
                        (size_t)M_TOT * D_ * sizeof(__hip_bfloat16));  // 4 MB

  hipLaunchKernelGGL(prep_fused, dim3(ROT_B + WT_B + CX_B), dim3(256), 0,
                     stream, x, theta, proj_w, xb, Wb);
  // grid: (M_TOT/256)=64 mt  x  8 e  x  (512/128)=4 nt  = 2048 blocks
  hipLaunchKernelGGL(gemm_xw, dim3(2048), dim3(256), 0, stream, xb, Wb, out);
}

// Round 13
// 103.990 us; speedup vs baseline: 1.2519x; 1.0088x over previous
//
#include <hip/hip_runtime.h>
#include <hip/hip_bf16.h>

#define E_ 8
#define B_ 8
#define S_ 2048
#define D_ 512
#define R_ 128
#define M_TOT (B_ * S_)   // 16384

typedef __attribute__((ext_vector_type(8))) short bf16x8;
typedef __attribute__((ext_vector_type(4))) float f32x4;
typedef __attribute__((ext_vector_type(4))) short s16x4;

__device__ __forceinline__ void gload_lds16(void* lds, const void* g) {
  __builtin_amdgcn_global_load_lds(
      (const __attribute__((address_space(1))) void*)g,
      (__attribute__((address_space(3))) void*)lds, 16, 0, 0);
}

// ---------------------------------------------------------------------------
// Fused prep kernel.
//   [0,32)        rotation: W[e] cols 0..128. ONE load phase (full 129-col
//                 slab in LDS), ONE in-LDS 128-step recurrence, ONE store
//                 phase — no per-chunk global round-trips (R12 had 8 serial
//                 phases on 16 CUs ~= 20-30us critical path).
//   [32,2080)     W tail cols 129..511 = bf16(proj_w)
//   [2080,6176)   x f32 -> bf16 (nontemporal loads)
// ---------------------------------------------------------------------------
#define ROT_B 32
#define WT_B 2048
#define CX_B 4096
__global__ __launch_bounds__(256) void prep_fused(
    const float* __restrict__ x, const float* __restrict__ theta,
    const float* __restrict__ pw, __hip_bfloat16* __restrict__ xb,
    __hip_bfloat16* __restrict__ Wb) {
  int blk = blockIdx.x;
  int t = threadIdx.x;
  if (blk < ROT_B) {
    // ---- rotation: all Givens planes are (0,k+1) -> per-row recurrence ----
    __shared__ float cs[R_], ss[R_];
    __shared__ float Pch[128][130];            // 130-stride: 2-way max (free)
    __shared__ __hip_bfloat16 Wch[128][130];
    int e = blk >> 2;
    int r0 = (blk & 3) * 128;
    if (t < R_) {
      float a = tanhf(theta[e * R_ + t]) * 0.1f;
      cs[t] = cosf(a);
      ss[t] = sinf(a);
    }
    const float* Pe = pw + (size_t)e * D_ * D_;
    __hip_bfloat16* We = Wb + (size_t)e * D_ * D_;
    // load P[r0..r0+127][0..128] in one coalesced phase
#pragma unroll 8
    for (int it = 0; it < 64; ++it) {
      int row = it * 2 + (t >> 7);
      int col = t & 127;
      Pch[row][col] = Pe[(size_t)(r0 + row) * D_ + col];
    }
    if (t < 128) Pch[t][128] = Pe[(size_t)(r0 + t) * D_ + 128];
    __syncthreads();
    if (t < 128) {
      float u = Pch[t][0];
#pragma unroll 16
      for (int k = 0; k < R_; ++k) {
        float pj = Pch[t][k + 1];
        Wch[t][k + 1] = __float2bfloat16(cs[k] * pj - ss[k] * u);
        u = cs[k] * u + ss[k] * pj;
      }
      Wch[t][0] = __float2bfloat16(u);
    }
    __syncthreads();
    // store W[r0..r0+127][0..128] in one coalesced phase
#pragma unroll 8
    for (int it = 0; it < 64; ++it) {
      int row = it * 2 + (t >> 7);
      int col = t & 127;
      We[(size_t)(r0 + row) * D_ + col] = Wch[row][col];
    }
    if (t < 128) We[(size_t)(r0 + t) * D_ + 128] = Wch[t][128];
  } else if (blk < ROT_B + WT_B) {
    // ---- W tail: cols 129..511 ----
    int g = (blk - ROT_B) * 256 + t;   // group over E*D*D/4
    int gidx = g & 127;                // d = gidx*4 .. +3
    if (gidx < 32) return;             // d <= 127 owned by rotation
    float4 v = ((const float4*)pw)[g];
    union { short4 s; __hip_bfloat16 h[4]; } u;
    u.h[0] = __float2bfloat16(v.x);
    u.h[1] = __float2bfloat16(v.y);
    u.h[2] = __float2bfloat16(v.z);
    u.h[3] = __float2bfloat16(v.w);
    if (gidx > 32) {
      ((short4*)Wb)[g] = u.s;
    } else {  // d = 128..131 -> write 129..131 only (128 owned by rotation)
      Wb[(size_t)g * 4 + 1] = u.h[1];
      Wb[(size_t)g * 4 + 2] = u.h[2];
      Wb[(size_t)g * 4 + 3] = u.h[3];
    }
  } else {
    // ---- x conversion: 2 f32x4 groups per thread, nontemporal loads ----
    int i = (blk - ROT_B - WT_B) * 256 + t;
#pragma unroll
    for (int rep = 0; rep < 2; ++rep) {
      int idx = i + rep * (CX_B * 256);
      f32x4 v = __builtin_nontemporal_load(&((const f32x4*)x)[idx]);
      union { s16x4 s; __hip_bfloat16 h[4]; } u;
      u.h[0] = __float2bfloat16(v.x);
      u.h[1] = __float2bfloat16(v.y);
      u.h[2] = __float2bfloat16(v.z);
      u.h[3] = __float2bfloat16(v.w);
      ((s16x4*)xb)[idx] = u.s;
    }
  }
}

// ---------------------------------------------------------------------------
// GEMM: out[e] = Xb @ Wb[e]^T (NT). Identical to R12 (best: 104.9us):
// 256x128 block, 4 waves, BK=32 double buffer, counted vmcnt(6), 2 blocks/CU,
// XCD swizzle, setprio, write-coalesced LDS-staged epilogue with NONTEMPORAL
// stores (C is write-once -> bypass L2, preserve operand residency).
// ---------------------------------------------------------------------------
__global__ __launch_bounds__(256, 2) void gemm_xw(
    const __hip_bfloat16* __restrict__ Xb,   // [M_TOT][512]
    const __hip_bfloat16* __restrict__ Wb,   // [E][512][512] rows=o, cols=d
    float* __restrict__ out)                 // [E][M_TOT][512]
{
  constexpr int BM = 256, BN = 128, BK = 32;
  constexpr int KD = D_, ND = D_;
  constexpr int NT = KD / BK;  // 16
  __shared__ __align__(16) char smem[49152];
  __hip_bfloat16 (*As)[BM * BK] =
      (__hip_bfloat16 (*)[BM * BK]) & smem[0];         // 2 x 16 KB
  __hip_bfloat16 (*Bs)[BN * BK] =
      (__hip_bfloat16 (*)[BN * BK]) & smem[32768];     // 2 x 8 KB
  float* Lep = (float*)&smem[0];                       // epilogue: 2x32x132 f32

  int bx = blockIdx.x;            // 2048 blocks
  int xcd = bx & 7, c = bx >> 3;  // chunk c in [0,256) per XCD
  int e = c >> 5;                 // 0..7  (e-major within XCD)
  int msub = (c >> 2) & 7;        // 0..7
  int nt = c & 3;                 // 0..3
  int mt = xcd * 8 + msub;        // 0..63

  int tid = threadIdx.x;
  int wave = tid >> 6, lane = tid & 63;
  int lr = lane & 15, lk = lane >> 4;
  int wm = wave >> 1, wn = wave & 1;   // 2x2 waves; wave-tile 128x64

  const __hip_bfloat16* Ag = Xb + (size_t)(mt * BM) * KD;
  const __hip_bfloat16* Bg = Wb + ((size_t)e * ND + (size_t)nt * BN) * KD;

  int srow = lane >> 2;
  int scol = (lane & 3) * 8;

  int aoff = (wm * 128 + lr) * BK + lk * 8;
  int boff = (wn * 64 + lr) * BK + lk * 8;

  f32x4 acc[8][4];
#pragma unroll
  for (int i = 0; i < 8; ++i)
#pragma unroll
    for (int j = 0; j < 4; ++j) acc[i][j] = (f32x4){0.f, 0.f, 0.f, 0.f};

#define STAGE(buf, t)                                                        \
  {                                                                          \
    _Pragma("unroll") for (int g = 0; g < 4; ++g) {                          \
      int rb = wave * 64 + g * 16;                                           \
      gload_lds16(&As[buf][rb * BK],                                         \
                  Ag + (size_t)(rb + srow) * KD + (t) * BK + scol);          \
    }                                                                        \
    _Pragma("unroll") for (int g = 0; g < 2; ++g) {                          \
      int rb = wave * 32 + g * 16;                                           \
      gload_lds16(&Bs[buf][rb * BK],                                         \
                  Bg + (size_t)(rb + srow) * KD + (t) * BK + scol);          \
    }                                                                        \
  }

  STAGE(0, 0);
  STAGE(1, 1);

#pragma unroll
  for (int t = 0; t < NT; ++t) {
    int buf = t & 1;
    if (t < NT - 1) {
      asm volatile("s_waitcnt vmcnt(6)" ::: "memory");
    } else {
      asm volatile("s_waitcnt vmcnt(0)" ::: "memory");
    }
    __builtin_amdgcn_s_barrier();   // tile t visible to all 4 waves

    bf16x8 af[8], bfr[4];
#pragma unroll
    for (int ni = 0; ni < 4; ++ni)
      bfr[ni] = *(const bf16x8*)&Bs[buf][boff + ni * 16 * BK];
#pragma unroll
    for (int mi = 0; mi < 8; ++mi)
      af[mi] = *(const bf16x8*)&As[buf][aoff + mi * 16 * BK];
    __builtin_amdgcn_s_setprio(1);
#pragma unroll
    for (int mi = 0; mi < 8; ++mi)
#pragma unroll
      for (int ni = 0; ni < 4; ++ni)
        acc[mi][ni] = __builtin_amdgcn_mfma_f32_16x16x32_bf16(
            af[mi], bfr[ni], acc[mi][ni], 0, 0, 0);
    __builtin_amdgcn_s_setprio(0);

    asm volatile("s_waitcnt lgkmcnt(0)" ::: "memory");
    __builtin_amdgcn_sched_barrier(0);
    __builtin_amdgcn_s_barrier();
    if (t + 2 < NT) STAGE(buf, t + 2);
  }
#undef STAGE

  // ---- write-coalesced epilogue (nontemporal stores) ----
  size_t obase = (size_t)e * M_TOT * ND;
  int row0 = mt * BM;
  int col0 = nt * BN;
  float* Lh = Lep + (size_t)wm * (32 * 132);
#pragma unroll
  for (int r = 0; r < 4; ++r) {
#pragma unroll
    for (int m2 = 0; m2 < 2; ++m2) {
      int mi = 2 * r + m2;
#pragma unroll
      for (int ni = 0; ni < 4; ++ni)
#pragma unroll
        for (int q = 0; q < 4; ++q)
          Lh[(m2 * 16 + lk * 4 + q) * 132 + wn * 64 + ni * 16 + lr] =
              acc[mi][ni][q];
    }
    __builtin_amdgcn_s_barrier();
#pragma unroll
    for (int j = 0; j < 8; ++j) {
      int lrow = wn * 16 + j * 2 + (lane >> 5);
      int lc4 = lane & 31;
      f32x4 v = *(const f32x4*)&Lh[lrow * 132 + lc4 * 4];
      int grow = row0 + wm * 128 + r * 32 + lrow;
      __builtin_nontemporal_store(
          v, (f32x4*)&out[obase + (size_t)grow * ND + col0 + lc4 * 4]);
    }
    __builtin_amdgcn_s_barrier();
  }
}

extern "C" void kernel_launch(void* const* d_in, const int* in_sizes, int n_in,
                              void* d_out, int out_size, void* d_ws, size_t ws_size,
                              hipStream_t stream) {
  const float* x = (const float*)d_in[0];        // [B][S][D] f32
  const float* theta = (const float*)d_in[1];    // [E][R] f32
  const float* proj_w = (const float*)d_in[2];   // [E][D][D] f32
  float* out = (float*)d_out;                    // [E][B][S][D] f32

  __hip_bfloat16* xb = (__hip_bfloat16*)d_ws;                          // 16 MB
  __hip_bfloat16* Wb = (__hip_bfloat16*)((char*)d_ws +
                        (size_t)M_TOT * D_ * sizeof(__hip_bfloat16));  // 4 MB

  hipLaunchKernelGGL(prep_fused, dim3(ROT_B + WT_B + CX_B), dim3(256), 0,
                     stream, x, theta, proj_w, xb, Wb);
  // grid: (M_TOT/256)=64 mt  x  8 e  x  (512/128)=4 nt  = 2048 blocks
  hipLaunchKernelGGL(gemm_xw, dim3(2048), dim3(256), 0, stream, xb, Wb, out);
}